// Round 12
// baseline (259.586 us; speedup 1.0000x reference)
//
#include <hip/hip_runtime.h>

#define NCOLS 256
#define NP    128
#define DD    256

typedef _Float16 half2 __attribute__((ext_vector_type(2)));
typedef _Float16 half4 __attribute__((ext_vector_type(4)));
typedef float    f32x4 __attribute__((ext_vector_type(4)));

// gfx950 spelling has no underscore before f16 (compiler-confirmed)
#define MFMA16(a,b,c) __builtin_amdgcn_mfma_f32_16x16x16f16(a,b,c,0,0,0)

// ---- workspace layout (bytes) ----
#define WS_COL_LN   0          // f32 [256][256]  LN(emb_column)
#define WS_LNP      262144     // f32 [128][256]  LN(emb_prompt)
#define WS_BASE     393216     // f32 [128][256]  base (prompt-side xp part)
#define WS_BLOG     524288     // f32 [128][256]  base_logits
#define WS_CW16     655360     // f16 CW in MFMA A-fragment order (see k0b)
#define WS_WB16     786432     // half2 [256][256] {w,b} interleaved feature emb

// ---- main LDS layout (bytes): x/g/b vectors + double-buffered 32-n chunk ----
#define LDS_CW0   3072         // 16 KB
#define LDS_XE0   19456        // 16 KB
#define LDS_CW1   35840        // 16 KB
#define LDS_XE1   52224        // 16 KB
#define SMEM_MAIN 68608        // 2 blocks/CU (137216 <= 163840) -> 16 waves/CU

// ============================ stage 0 kernels ============================

// blocks 0..255: LN rows of emb_column; 256..383: LN rows of emb_prompt;
// 384..511: half2 {w,b} interleave of feature emb weights.
__global__ __launch_bounds__(256) void k0a(
    const float* __restrict__ emb_column, const float* __restrict__ emb_prompt,
    const float* __restrict__ ln_col_g, const float* __restrict__ ln_col_b,
    const float* __restrict__ ln_prompt_g, const float* __restrict__ ln_prompt_b,
    const float* __restrict__ few, const float* __restrict__ feb,
    char* __restrict__ ws)
{
    __shared__ float red[10];
    int blk = blockIdx.x, tid = threadIdx.x;
    if (blk < 384) {
        const float *src, *g, *bb; float* dst;
        if (blk < 256) { int r = blk;     src = emb_column + r*DD; g = ln_col_g;    bb = ln_col_b;    dst = (float*)(ws + WS_COL_LN) + r*DD; }
        else           { int r = blk-256; src = emb_prompt + r*DD; g = ln_prompt_g; bb = ln_prompt_b; dst = (float*)(ws + WS_LNP) + r*DD; }
        float v = src[tid];
        float s = v, q = v*v;
        #pragma unroll
        for (int off = 32; off; off >>= 1) { s += __shfl_xor(s, off); q += __shfl_xor(q, off); }
        int wid = tid >> 6, lane = tid & 63;
        if (lane == 0) { red[wid] = s; red[4+wid] = q; }
        __syncthreads();
        if (tid == 0) {
            float S = red[0]+red[1]+red[2]+red[3];
            float Q = red[4]+red[5]+red[6]+red[7];
            float mu = S * (1.0f/DD);
            float var = Q * (1.0f/DD) - mu*mu;
            red[8] = mu; red[9] = rsqrtf(var + 1e-5f);
        }
        __syncthreads();
        dst[tid] = (v - red[8]) * red[9] * g[tid] + bb[tid];
    } else {
        int base = (blk - 384) * 512;
        half2* wb = (half2*)(ws + WS_WB16);
        #pragma unroll
        for (int j = 0; j < 2; ++j) {
            int idx = base + j*256 + tid;      // 0..65535
            half2 h; h[0] = (_Float16)few[idx]; h[1] = (_Float16)feb[idx];
            wb[idx] = h;
        }
    }
}

// blocks 0..255: CW[n][k] = sum_d col_ln[n][d] * diw[d][256+k], stored in
//   MFMA A-fragment order: f16 index ((kc*16+nt)*64 + lq*16 + lr)*4 + j
//   with n = 16nt+lr, k = 16kc+4lq+j.
// blocks 256..383: base[p][d] = sum_k LNp[p][k]*diw[d][k] + dib[d] + emb_prompt[p][d]
__global__ __launch_bounds__(256) void k0b(
    const float* __restrict__ diw, const float* __restrict__ dib,
    const float* __restrict__ emb_prompt, char* __restrict__ ws)
{
    __shared__ float rowv[DD];
    int blk = blockIdx.x, tid = threadIdx.x;
    if (blk < 256) {
        int n = blk;
        const float* col_ln = (const float*)(ws + WS_COL_LN);
        rowv[tid] = col_ln[n*DD + tid];
        __syncthreads();
        float acc = 0.f;
        #pragma unroll 4
        for (int d = 0; d < DD; ++d) acc += rowv[d] * diw[d*512 + 256 + tid];
        int nt = n >> 4, lr = n & 15;
        int kc = tid >> 4, lq = (tid >> 2) & 3, j = tid & 3;
        ((_Float16*)(ws + WS_CW16))[((kc*16 + nt)*64 + lq*16 + lr)*4 + j] = (_Float16)acc;
    } else {
        int p = blk - 256;
        const float* lnp = (const float*)(ws + WS_LNP);
        rowv[tid] = lnp[p*DD + tid];
        __syncthreads();
        float acc = 0.f;
        #pragma unroll 4
        for (int k = 0; k < DD; ++k) acc += rowv[k] * diw[tid*512 + k];
        ((float*)(ws + WS_BASE))[p*DD + tid] = acc + dib[tid] + emb_prompt[p*DD + tid];
    }
}

// base_logits[p][n] = sum_d base[p][d] * col_ln[n][d]
__global__ __launch_bounds__(256) void k0c(char* __restrict__ ws)
{
    __shared__ float bs[DD];
    int p = blockIdx.x, n = threadIdx.x;
    const float* base   = (const float*)(ws + WS_BASE);
    const float* col_ln = (const float*)(ws + WS_COL_LN);
    bs[n] = base[p*DD + n];
    __syncthreads();
    float acc = 0.f;
    #pragma unroll 4
    for (int d = 0; d < DD; ++d) acc += bs[d] * col_ln[n*DD + d];
    ((float*)(ws + WS_BLOG))[p*DD + n] = acc;
}

// ============================ main kernel ============================
// 1 block = 1 batch (grid 1024, 512 thr, 8 waves). LDS 67.6 KB -> 2
// blocks/CU -> 16 waves/CU (4/SIMD) at the (512,2) 256-reg regime
// (compiled VGPR ~108 <= 128 allows 4 waves/SIMD in HW).
// Wave w owns p-rows [16w,16w+16) x all 256 d. Flash loop, 8 n-chunks
// of 32. Per chunk: CW slice reg-staged to LDS (loads issued early),
// xe slice computed on the fly into LDS (never HBM), double-buffered;
// single barrier per chunk.
__global__ __launch_bounds__(512, 2) void trompt_main(
    const float* __restrict__ x, const float* __restrict__ prev,
    const float* __restrict__ expand_w, const float* __restrict__ expand_b,
    const float* __restrict__ ln_emb_g, const float* __restrict__ ln_emb_b,
    const char* __restrict__ ws, float* __restrict__ out)
{
    extern __shared__ char smem[];
    float* x_s  = (float*)(smem);
    float* g_s  = (float*)(smem + 1024);
    float* bb_s = (float*)(smem + 2048);

    const char*  cwbase = ws + WS_CW16;
    const half2* WB     = (const half2*)(ws + WS_WB16);   // [n][d] {w,b}

    int b = blockIdx.x;
    int tid = threadIdx.x;
    int w = tid >> 6, l = tid & 63, lq = l >> 4, lr = l & 15;
    int p = 16*w + lr;

    if (tid < 256) {
        x_s[tid]  = x[b*NCOLS + tid];
        g_s[tid]  = ln_emb_g[tid];
        bb_s[tid] = ln_emb_b[tid];
    }

    // prev row -> f16 B-fragments (32 VGPRs), live across all chunks
    half4 pfrag[16];
    {
        const float* prow = prev + ((size_t)b*NP + p)*DD + 4*lq;
        #pragma unroll
        for (int kc = 0; kc < 16; ++kc) {
            f32x4 v = *(const f32x4*)(prow + 16*kc);
            half4 h;
            #pragma unroll
            for (int j = 0; j < 4; ++j) h[j] = (_Float16)v[j];
            pfrag[kc] = h;
        }
    }

    // CW chunk staging: 16 KB -> LDS; 32 B/thread as 2x16B.
    // slice frag (kc*16 + 2c + nt), nt in {0,1} -> lds (kc*2 + nt)*512 + lane*8
    auto stage_cw = [&](int c, char* dstbuf) {
        #pragma unroll
        for (int i = 0; i < 2; ++i) {
            int u = tid + 512*i;                  // 0..1023, 16B each
            int kc = u >> 6, nt = (u >> 5) & 1, rem = u & 31;
            uint4 v = *(const uint4*)(cwbase + kc*8192 + c*1024 + nt*512 + rem*16);
            *(uint4*)(dstbuf + u*16) = v;
        }
    };

    // xe chunk compute: 32 n-rows -> f16 fragment buffer; 4 rows/wave.
    // chunk-local n = 16*kc2 + 4*lq2 + j (kc2 = w>>2, lq2 = w&3);
    // frag (kc2*16+dt) at byte (((kc2*16+dt)*64) + lq2*16 + lr)*8.
    auto compute_xe = [&](int c, char* xebuf) {
        int kc2 = w >> 2, lq2 = w & 3;
        float vj[4][4];                           // [j][cc]
        #pragma unroll
        for (int j = 0; j < 4; ++j) {
            int n = c*32 + 16*kc2 + 4*lq2 + j;
            float xv = x_s[n];
            const half2* wbrow = WB + n*DD;
            float s = 0.f, q = 0.f;
            #pragma unroll
            for (int cc = 0; cc < 4; ++cc) {
                half2 pp = wbrow[l + 64*cc];
                float e = fmaf(xv, (float)pp[0], (float)pp[1]);
                e = e > 0.f ? e : 0.f;
                vj[j][cc] = e; s += e; q += e*e;
            }
            #pragma unroll
            for (int off = 32; off; off >>= 1) { s += __shfl_xor(s, off); q += __shfl_xor(q, off); }
            float mu = s * (1.0f/DD);
            float rs = rsqrtf(q*(1.0f/DD) - mu*mu + 1e-5f);
            #pragma unroll
            for (int cc = 0; cc < 4; ++cc) {
                int d = l + 64*cc;
                vj[j][cc] = (vj[j][cc]-mu)*rs*g_s[d] + bb_s[d];
            }
        }
        #pragma unroll
        for (int cc = 0; cc < 4; ++cc) {
            int dt = 4*cc + (l >> 4);
            half4 h;
            #pragma unroll
            for (int j = 0; j < 4; ++j) h[j] = (_Float16)vj[j][cc];
            *(half4*)(xebuf + (((kc2*16 + dt)*64) + lq2*16 + lr)*8) = h;
        }
    };

    // prologue: buf0 = CW(0) + xe(0)
    stage_cw(0, smem + LDS_CW0);
    __syncthreads();                 // x_s ready (and CW0 written)
    compute_xe(0, smem + LDS_XE0);

    f32x4 acc_v[16];                 // 16p x 256d: d = 16*dt + 4lq + r
    #pragma unroll
    for (int dt = 0; dt < 16; ++dt) acc_v[dt] = (f32x4){0.f,0.f,0.f,0.f};
    float m = -1e30f, ll = 0.f;

    const float* blrow = (const float*)(ws + WS_BLOG) + (size_t)p*DD + 4*lq;

    __syncthreads();                 // buf0 complete

    for (int c = 0; c < 8; ++c) {
        char* cwc = smem + ((c & 1) ? LDS_CW1 : LDS_CW0);
        char* xec = smem + ((c & 1) ? LDS_XE1 : LDS_XE0);
        char* cwn = smem + ((c & 1) ? LDS_CW0 : LDS_CW1);
        char* xen = smem + ((c & 1) ? LDS_XE0 : LDS_XE1);

        // issue next chunk's CW global loads early (land during logits MFMA)
        uint4 st[2];
        if (c < 7) {
            #pragma unroll
            for (int i = 0; i < 2; ++i) {
                int u = tid + 512*i;
                int kc = u >> 6, nt = (u >> 5) & 1, rem = u & 31;
                st[i] = *(const uint4*)(cwbase + kc*8192 + (c+1)*1024 + nt*512 + rem*16);
            }
        }

        // ---- logits chunk: 16p x 32n, C-init from base_logits ----
        f32x4 acc_c[2];
        #pragma unroll
        for (int nt = 0; nt < 2; ++nt) acc_c[nt] = *(const f32x4*)(blrow + 32*c + 16*nt);
        const char* cwl = cwc + l*8;
        #pragma unroll
        for (int kc = 0; kc < 16; ++kc) {
            const char* fb = cwl + kc*1024;
            half4 a0 = *(const half4*)(fb);
            half4 a1 = *(const half4*)(fb + 512);
            half4 bp = pfrag[kc];
            acc_c[0] = MFMA16(a0, bp, acc_c[0]);
            acc_c[1] = MFMA16(a1, bp, acc_c[1]);
        }

        // ---- online softmax update (p lane-local across lq: 2 shfls) ----
        float pmax = fmaxf(fmaxf(fmaxf(acc_c[0][0], acc_c[0][1]), fmaxf(acc_c[0][2], acc_c[0][3])),
                           fmaxf(fmaxf(acc_c[1][0], acc_c[1][1]), fmaxf(acc_c[1][2], acc_c[1][3])));
        pmax = fmaxf(pmax, __shfl_xor(pmax, 16));
        pmax = fmaxf(pmax, __shfl_xor(pmax, 32));
        float mnew = fmaxf(m, pmax);
        float f = __expf(m - mnew);
        m = mnew;
        ll *= f;
        #pragma unroll
        for (int dt = 0; dt < 16; ++dt)
            #pragma unroll
            for (int r = 0; r < 4; ++r) acc_v[dt][r] *= f;

        float csum = 0.f;
        half4 p16c[2];
        #pragma unroll
        for (int nt = 0; nt < 2; ++nt) {
            half4 h;
            #pragma unroll
            for (int r = 0; r < 4; ++r) {
                float e = __expf(acc_c[nt][r] - m);
                csum += e;
                h[r] = (_Float16)e;
            }
            p16c[nt] = h;
        }
        csum += __shfl_xor(csum, 16);
        csum += __shfl_xor(csum, 32);
        ll += csum;

        // ---- fill next chunk's buffer (nobody reads it this chunk) ----
        if (c < 7) {
            compute_xe(c+1, xen);
            #pragma unroll
            for (int i = 0; i < 2; ++i) {
                int u = tid + 512*i;
                *(uint4*)(cwn + u*16) = st[i];
            }
        }

        // ---- PV: acc_v += xe_chunk^T @ P_chunk (A-frags from LDS) ----
        const char* xel = xec + l*8;
        #pragma unroll
        for (int kc2 = 0; kc2 < 2; ++kc2) {
            half4 bp = p16c[kc2];
            const char* xb = xel + kc2*8192;
            #pragma unroll
            for (int dt = 0; dt < 16; ++dt) {
                half4 a = *(const half4*)(xb + dt*512);
                acc_v[dt] = MFMA16(a, bp, acc_v[dt]);
            }
        }

        __syncthreads();             // chunk done; next buffer complete
    }

    // epilogue: out = (V/ll)*sw + sb; col p = lane lr, rows d = 16dt+4lq+r
    {
        float sw = (1.0f + expand_w[p]) / ll;
        float sb = expand_b[p];
        float* orow = out + ((size_t)b*NP + p)*DD + 4*lq;
        #pragma unroll
        for (int dt = 0; dt < 16; ++dt) {
            f32x4 v = acc_v[dt];
            #pragma unroll
            for (int r = 0; r < 4; ++r) v[r] = v[r]*sw + sb;
            *(f32x4*)(orow + 16*dt) = v;
        }
    }
}

// ============================ launcher ============================
extern "C" void kernel_launch(void* const* d_in, const int* in_sizes, int n_in,
                              void* d_out, int out_size, void* d_ws, size_t ws_size,
                              hipStream_t stream) {
    (void)in_sizes; (void)n_in; (void)out_size; (void)ws_size;
    const float* x           = (const float*)d_in[0];
    const float* prev        = (const float*)d_in[1];
    const float* few         = (const float*)d_in[2];
    const float* feb         = (const float*)d_in[3];
    const float* ln_emb_g    = (const float*)d_in[4];
    const float* ln_emb_b    = (const float*)d_in[5];
    const float* ln_col_g    = (const float*)d_in[6];
    const float* ln_col_b    = (const float*)d_in[7];
    const float* ln_prompt_g = (const float*)d_in[8];
    const float* ln_prompt_b = (const float*)d_in[9];
    const float* diw         = (const float*)d_in[10];
    const float* dib         = (const float*)d_in[11];
    const float* emb_column  = (const float*)d_in[12];
    const float* emb_prompt  = (const float*)d_in[13];
    const float* expand_w    = (const float*)d_in[14];
    const float* expand_b    = (const float*)d_in[15];
    char* ws = (char*)d_ws;
    float* out = (float*)d_out;

    k0a<<<512, 256, 0, stream>>>(emb_column, emb_prompt, ln_col_g, ln_col_b,
                                 ln_prompt_g, ln_prompt_b, few, feb, ws);
    k0b<<<384, 256, 0, stream>>>(diw, dib, emb_prompt, ws);
    k0c<<<128, 256, 0, stream>>>(ws);

    (void)hipFuncSetAttribute(reinterpret_cast<const void*>(trompt_main),
                              hipFuncAttributeMaxDynamicSharedMemorySize, SMEM_MAIN);
    trompt_main<<<1024, 512, SMEM_MAIN, stream>>>(x, prev, expand_w, expand_b,
                                                  ln_emb_g, ln_emb_b, ws, out);
}

// Round 13
// 218.852 us; speedup vs baseline: 1.1861x; 1.1861x over previous
//
#include <hip/hip_runtime.h>

#define NCOLS 256
#define NP    128
#define DD    256

typedef _Float16 half2 __attribute__((ext_vector_type(2)));
typedef _Float16 half4 __attribute__((ext_vector_type(4)));
typedef float    f32x4 __attribute__((ext_vector_type(4)));

// gfx950 spelling has no underscore before f16 (compiler-confirmed)
#define MFMA16(a,b,c) __builtin_amdgcn_mfma_f32_16x16x16f16(a,b,c,0,0,0)

// ---- workspace layout (bytes) ----
#define WS_COL_LN   0          // f32 [256][256]  LN(emb_column)
#define WS_LNP      262144     // f32 [128][256]  LN(emb_prompt)
#define WS_BASE     393216     // f32 [128][256]  base (prompt-side xp part)
#define WS_BLOG     524288     // f32 [128][256]  base_logits
#define WS_CW16     655360     // f16 CW in MFMA A-fragment order (see k0b)
#define WS_WB16     786432     // half2 [256][256] {w,b} interleaved feature emb

// k_logit LDS: CW dbuf 2x32KB @0; sm_m @65536 (512B x2 halves); sm_l @66560
#define SMEM_LOGIT 67584
// k_pv LDS: x_s @0 (1KB); xe dbuf 16KB @2048 / @18432
#define SMEM_PV    34816

// ============================ stage 0 kernels ============================

__global__ __launch_bounds__(256) void k0a(
    const float* __restrict__ emb_column, const float* __restrict__ emb_prompt,
    const float* __restrict__ ln_col_g, const float* __restrict__ ln_col_b,
    const float* __restrict__ ln_prompt_g, const float* __restrict__ ln_prompt_b,
    const float* __restrict__ few, const float* __restrict__ feb,
    char* __restrict__ ws)
{
    __shared__ float red[10];
    int blk = blockIdx.x, tid = threadIdx.x;
    if (blk < 384) {
        const float *src, *g, *bb; float* dst;
        if (blk < 256) { int r = blk;     src = emb_column + r*DD; g = ln_col_g;    bb = ln_col_b;    dst = (float*)(ws + WS_COL_LN) + r*DD; }
        else           { int r = blk-256; src = emb_prompt + r*DD; g = ln_prompt_g; bb = ln_prompt_b; dst = (float*)(ws + WS_LNP) + r*DD; }
        float v = src[tid];
        float s = v, q = v*v;
        #pragma unroll
        for (int off = 32; off; off >>= 1) { s += __shfl_xor(s, off); q += __shfl_xor(q, off); }
        int wid = tid >> 6, lane = tid & 63;
        if (lane == 0) { red[wid] = s; red[4+wid] = q; }
        __syncthreads();
        if (tid == 0) {
            float S = red[0]+red[1]+red[2]+red[3];
            float Q = red[4]+red[5]+red[6]+red[7];
            float mu = S * (1.0f/DD);
            float var = Q * (1.0f/DD) - mu*mu;
            red[8] = mu; red[9] = rsqrtf(var + 1e-5f);
        }
        __syncthreads();
        dst[tid] = (v - red[8]) * red[9] * g[tid] + bb[tid];
    } else {
        int base = (blk - 384) * 512;
        half2* wb = (half2*)(ws + WS_WB16);
        #pragma unroll
        for (int j = 0; j < 2; ++j) {
            int idx = base + j*256 + tid;      // 0..65535
            half2 h; h[0] = (_Float16)few[idx]; h[1] = (_Float16)feb[idx];
            wb[idx] = h;
        }
    }
}

// blocks 0..255: CW[n][k] = sum_d col_ln[n][d] * diw[d][256+k], stored in
//   MFMA A-fragment order: f16 index ((kc*16+nt)*64 + lq*16 + lr)*4 + j
//   with n = 16nt+lr, k = 16kc+4lq+j.
// blocks 256..383: base[p][d] = sum_k LNp[p][k]*diw[d][k] + dib[d] + emb_prompt[p][d]
__global__ __launch_bounds__(256) void k0b(
    const float* __restrict__ diw, const float* __restrict__ dib,
    const float* __restrict__ emb_prompt, char* __restrict__ ws)
{
    __shared__ float rowv[DD];
    int blk = blockIdx.x, tid = threadIdx.x;
    if (blk < 256) {
        int n = blk;
        const float* col_ln = (const float*)(ws + WS_COL_LN);
        rowv[tid] = col_ln[n*DD + tid];
        __syncthreads();
        float acc = 0.f;
        #pragma unroll 4
        for (int d = 0; d < DD; ++d) acc += rowv[d] * diw[d*512 + 256 + tid];
        int nt = n >> 4, lr = n & 15;
        int kc = tid >> 4, lq = (tid >> 2) & 3, j = tid & 3;
        ((_Float16*)(ws + WS_CW16))[((kc*16 + nt)*64 + lq*16 + lr)*4 + j] = (_Float16)acc;
    } else {
        int p = blk - 256;
        const float* lnp = (const float*)(ws + WS_LNP);
        rowv[tid] = lnp[p*DD + tid];
        __syncthreads();
        float acc = 0.f;
        #pragma unroll 4
        for (int k = 0; k < DD; ++k) acc += rowv[k] * diw[tid*512 + k];
        ((float*)(ws + WS_BASE))[p*DD + tid] = acc + dib[tid] + emb_prompt[p*DD + tid];
    }
}

// base_logits[p][n] = sum_d base[p][d] * col_ln[n][d]
__global__ __launch_bounds__(256) void k0c(char* __restrict__ ws)
{
    __shared__ float bs[DD];
    int p = blockIdx.x, n = threadIdx.x;
    const float* base   = (const float*)(ws + WS_BASE);
    const float* col_ln = (const float*)(ws + WS_COL_LN);
    bs[n] = base[p*DD + n];
    __syncthreads();
    float acc = 0.f;
    #pragma unroll 4
    for (int d = 0; d < DD; ++d) acc += bs[d] * col_ln[n*DD + d];
    ((float*)(ws + WS_BLOG))[p*DD + n] = acc;
}

// ============================ k_logit ============================
// grid 2048: b = bid>>1, ph = bid&1 (64 p-rows). 512 thr, 8 waves.
// Wave w: p-tile pt=w>>1 (16 rows), n-half nh=w&1 (128 cols) -> acc is
// only 8 f32x4 (32 AGPR); + pfrag 32 -> ~100 regs -> 4 waves/SIMD,
// 2 blocks/CU. CW LDS-staged, double-buffered, 4 chunks of 64 n.
// Full softmax (pair halves combined via 1KB LDS), normalized P (f16)
// written into the first 64KB of out[b]'s 128KB (k_pv reads then
// overwrites after a barrier).
__global__ __launch_bounds__(512, 4) void k_logit(
    const float* __restrict__ prev, const char* __restrict__ ws,
    char* __restrict__ pbuf)
{
    extern __shared__ char smem[];
    float* sm_m = (float*)(smem + 65536);
    float* sm_l = (float*)(smem + 66560);

    const char* cwbase = ws + WS_CW16;

    int bid = blockIdx.x;
    int b = bid >> 1, ph = bid & 1;
    int tid = threadIdx.x;
    int w = tid >> 6, l = tid & 63, lq = l >> 4, lr = l & 15;
    int pt = w >> 1, nh = w & 1;
    int pl = 16*pt + lr;             // local p 0..63
    int p  = 64*ph + pl;             // global p

    // prev row -> f16 B-fragments (32 VGPRs); pair duplicates (L2 hit)
    half4 pfrag[16];
    {
        const float* prow = prev + ((size_t)b*NP + p)*DD + 4*lq;
        #pragma unroll
        for (int kc = 0; kc < 16; ++kc) {
            f32x4 v = *(const f32x4*)(prow + 16*kc);
            half4 h;
            #pragma unroll
            for (int j = 0; j < 4; ++j) h[j] = (_Float16)v[j];
            pfrag[kc] = h;
        }
    }

    // CW chunk staging: 32 KB (64 n) -> LDS; 64 B/thread as 4x16B.
    // frag (kc, ntg) -> lds kc*2048 + ntg*512 + lane*8
    auto stage_cw = [&](int c, char* dst) {
        #pragma unroll
        for (int i = 0; i < 4; ++i) {
            int u = tid + 512*i;                  // 0..2047 (16B units)
            int kc = u >> 7, ntg = (u >> 5) & 3, rem = u & 31;
            uint4 v = *(const uint4*)(cwbase + kc*8192 + c*2048 + ntg*512 + rem*16);
            *(uint4*)(dst + u*16) = v;
        }
    };

    // acc: 8 x f32x4 -> (n = 16*(4c+2nh+t) + 4lq + r, p), C-init from blog
    f32x4 acc[8];
    {
        const float* blrow = (const float*)(ws + WS_BLOG) + (size_t)p*DD + 4*lq;
        #pragma unroll
        for (int a = 0; a < 8; ++a)
            acc[a] = *(const f32x4*)(blrow + 16*(4*(a>>1) + 2*nh + (a&1)));
    }

    stage_cw(0, smem);
    __syncthreads();

    #pragma unroll
    for (int c = 0; c < 4; ++c) {
        char* cwc = smem + ((c & 1) ? 32768 : 0);
        char* cwn = smem + ((c & 1) ? 0 : 32768);

        uint4 st[4];
        if (c < 3) {
            #pragma unroll
            for (int i = 0; i < 4; ++i) {
                int u = tid + 512*i;
                int kc = u >> 7, ntg = (u >> 5) & 3, rem = u & 31;
                st[i] = *(const uint4*)(cwbase + kc*8192 + (c+1)*2048 + ntg*512 + rem*16);
            }
        }

        const char* cwl = cwc + l*8 + nh*1024;
        #pragma unroll
        for (int kc = 0; kc < 16; ++kc) {
            const char* fb = cwl + kc*2048;
            half4 a0 = *(const half4*)(fb);
            half4 a1 = *(const half4*)(fb + 512);
            half4 bp = pfrag[kc];
            acc[2*c]   = MFMA16(a0, bp, acc[2*c]);
            acc[2*c+1] = MFMA16(a1, bp, acc[2*c+1]);
        }

        if (c < 3) {
            #pragma unroll
            for (int i = 0; i < 4; ++i) {
                int u = tid + 512*i;
                *(uint4*)(cwn + u*16) = st[i];
            }
        }
        __syncthreads();
    }

    // ---- softmax over full row (pair halves combined via LDS) ----
    float pmax = -1e30f;
    #pragma unroll
    for (int a = 0; a < 8; ++a)
        #pragma unroll
        for (int r = 0; r < 4; ++r) pmax = fmaxf(pmax, acc[a][r]);
    pmax = fmaxf(pmax, __shfl_xor(pmax, 16));
    pmax = fmaxf(pmax, __shfl_xor(pmax, 32));
    if (lq == 0) sm_m[nh*64 + pl] = pmax;
    __syncthreads();
    float m = fmaxf(pmax, sm_m[(1 ^ nh)*64 + pl]);

    float s = 0.f;
    #pragma unroll
    for (int a = 0; a < 8; ++a)
        #pragma unroll
        for (int r = 0; r < 4; ++r) { float e = __expf(acc[a][r] - m); acc[a][r] = e; s += e; }
    s += __shfl_xor(s, 16);
    s += __shfl_xor(s, 32);
    if (lq == 0) sm_l[nh*64 + pl] = s;
    __syncthreads();
    float inv = 1.0f / (s + sm_l[(1 ^ nh)*64 + pl]);

    // ---- write normalized P (f16) at byte p*512 + n*2 ----
    char* Pb = pbuf + (size_t)b*131072;
    #pragma unroll
    for (int a = 0; a < 8; ++a) {
        int NT = 4*(a >> 1) + 2*nh + (a & 1);
        half4 h;
        #pragma unroll
        for (int r = 0; r < 4; ++r) h[r] = (_Float16)(acc[a][r] * inv);
        *(half4*)(Pb + p*512 + NT*32 + lq*8) = h;
    }
}

// ============================ k_pv ============================
// grid 1024 (1 block = 1 batch), 512 thr, 8 waves. Wave w: p-rows
// [16w,16w+16) x all 256 d. 8 chunks of 32 n: compute_xe -> LDS dbuf,
// P f16 frags read from pbuf (8B/lane/kc2), PV MFMA. acc_v 64 AGPR +
// ~60 arch -> 2 blocks/CU. Final barrier covers the P-alias overwrite.
__global__ __launch_bounds__(512, 4) void k_pv(
    const float* __restrict__ x,
    const float* __restrict__ expand_w, const float* __restrict__ expand_b,
    const float* __restrict__ ln_emb_g, const float* __restrict__ ln_emb_b,
    const char* __restrict__ ws, float* __restrict__ out)
{
    extern __shared__ char smem[];
    float* x_s = (float*)smem;
    char* xe0 = smem + 2048;
    char* xe1 = smem + 18432;

    const half2* WB = (const half2*)(ws + WS_WB16);   // [n][d] {w,b}

    int b = blockIdx.x;
    int tid = threadIdx.x;
    int w = tid >> 6, l = tid & 63, lq = l >> 4, lr = l & 15;
    int p = 16*w + lr;

    if (tid < 256) x_s[tid] = x[b*NCOLS + tid];
    float gcc[4], bcc[4];
    #pragma unroll
    for (int cc = 0; cc < 4; ++cc) {
        gcc[cc] = ln_emb_g[l + 64*cc];
        bcc[cc] = ln_emb_b[l + 64*cc];
    }

    const char* Pb = (const char*)out + (size_t)b*131072;

    // xe chunk compute: 32 n-rows -> f16 fragment buffer; 4 rows/wave.
    auto compute_xe = [&](int c, char* xebuf) {
        int kc2 = w >> 2, lq2 = w & 3;
        float vj[4][4];
        #pragma unroll
        for (int j = 0; j < 4; ++j) {
            int n = c*32 + 16*kc2 + 4*lq2 + j;
            float xv = x_s[n];
            const half2* wbrow = WB + n*DD;
            float s = 0.f, q = 0.f;
            #pragma unroll
            for (int cc = 0; cc < 4; ++cc) {
                half2 pp = wbrow[l + 64*cc];
                float e = fmaf(xv, (float)pp[0], (float)pp[1]);
                e = e > 0.f ? e : 0.f;
                vj[j][cc] = e; s += e; q += e*e;
            }
            #pragma unroll
            for (int off = 32; off; off >>= 1) { s += __shfl_xor(s, off); q += __shfl_xor(q, off); }
            float mu = s * (1.0f/DD);
            float rs = rsqrtf(q*(1.0f/DD) - mu*mu + 1e-5f);
            #pragma unroll
            for (int cc = 0; cc < 4; ++cc)
                vj[j][cc] = (vj[j][cc]-mu)*rs*gcc[cc] + bcc[cc];
        }
        #pragma unroll
        for (int cc = 0; cc < 4; ++cc) {
            int dt = 4*cc + (l >> 4);
            half4 h;
            #pragma unroll
            for (int j = 0; j < 4; ++j) h[j] = (_Float16)vj[j][cc];
            *(half4*)(xebuf + (((kc2*16 + dt)*64) + lq2*16 + lr)*8) = h;
        }
    };

    __syncthreads();                 // x_s ready
    compute_xe(0, xe0);

    f32x4 acc_v[16];
    #pragma unroll
    for (int dt = 0; dt < 16; ++dt) acc_v[dt] = (f32x4){0.f,0.f,0.f,0.f};

    __syncthreads();                 // xe0 complete

    for (int c = 0; c < 8; ++c) {
        char* xec = (c & 1) ? xe1 : xe0;
        char* xen = (c & 1) ? xe0 : xe1;

        // P B-fragments for this chunk (issued early; 8B per kc2)
        half4 p16c[2];
        #pragma unroll
        for (int kc2 = 0; kc2 < 2; ++kc2)
            p16c[kc2] = *(const half4*)(Pb + p*512 + c*64 + kc2*32 + lq*8);

        if (c < 7) compute_xe(c+1, xen);

        const char* xel = xec + l*8;
        #pragma unroll
        for (int kc2 = 0; kc2 < 2; ++kc2) {
            half4 bp = p16c[kc2];
            const char* xb = xel + kc2*8192;
            #pragma unroll
            for (int dt = 0; dt < 16; ++dt) {
                half4 a = *(const half4*)(xb + dt*512);
                acc_v[dt] = MFMA16(a, bp, acc_v[dt]);
            }
        }

        __syncthreads();             // xen complete; also fences P reads
    }

    // epilogue: out = V*sw + sb (P was pre-normalized); overwrites P region
    {
        float sw = 1.0f + expand_w[p];
        float sb = expand_b[p];
        float* orow = out + ((size_t)b*NP + p)*DD + 4*lq;
        #pragma unroll
        for (int dt = 0; dt < 16; ++dt) {
            f32x4 v = acc_v[dt];
            #pragma unroll
            for (int r = 0; r < 4; ++r) v[r] = v[r]*sw + sb;
            *(f32x4*)(orow + 16*dt) = v;
        }
    }
}

// ============================ launcher ============================
extern "C" void kernel_launch(void* const* d_in, const int* in_sizes, int n_in,
                              void* d_out, int out_size, void* d_ws, size_t ws_size,
                              hipStream_t stream) {
    (void)in_sizes; (void)n_in; (void)out_size; (void)ws_size;
    const float* x           = (const float*)d_in[0];
    const float* prev        = (const float*)d_in[1];
    const float* few         = (const float*)d_in[2];
    const float* feb         = (const float*)d_in[3];
    const float* ln_emb_g    = (const float*)d_in[4];
    const float* ln_emb_b    = (const float*)d_in[5];
    const float* ln_col_g    = (const float*)d_in[6];
    const float* ln_col_b    = (const float*)d_in[7];
    const float* ln_prompt_g = (const float*)d_in[8];
    const float* ln_prompt_b = (const float*)d_in[9];
    const float* diw         = (const float*)d_in[10];
    const float* dib         = (const float*)d_in[11];
    const float* emb_column  = (const float*)d_in[12];
    const float* emb_prompt  = (const float*)d_in[13];
    const float* expand_w    = (const float*)d_in[14];
    const float* expand_b    = (const float*)d_in[15];
    char* ws = (char*)d_ws;
    float* out = (float*)d_out;

    k0a<<<512, 256, 0, stream>>>(emb_column, emb_prompt, ln_col_g, ln_col_b,
                                 ln_prompt_g, ln_prompt_b, few, feb, ws);
    k0b<<<384, 256, 0, stream>>>(diw, dib, emb_prompt, ws);
    k0c<<<128, 256, 0, stream>>>(ws);

    (void)hipFuncSetAttribute(reinterpret_cast<const void*>(k_logit),
                              hipFuncAttributeMaxDynamicSharedMemorySize, SMEM_LOGIT);
    k_logit<<<2048, 512, SMEM_LOGIT, stream>>>(prev, ws, (char*)d_out);

    (void)hipFuncSetAttribute(reinterpret_cast<const void*>(k_pv),
                              hipFuncAttributeMaxDynamicSharedMemorySize, SMEM_PV);
    k_pv<<<1024, 512, SMEM_PV, stream>>>(x, expand_w, expand_b,
                                         ln_emb_g, ln_emb_b, ws, out);
}

// Round 15
// 195.482 us; speedup vs baseline: 1.3279x; 1.1195x over previous
//
#include <hip/hip_runtime.h>

#define NCOLS 256
#define NP    128
#define DD    256

typedef _Float16 half2 __attribute__((ext_vector_type(2)));
typedef _Float16 half4 __attribute__((ext_vector_type(4)));
typedef float    f32x4 __attribute__((ext_vector_type(4)));

// gfx950 spelling has no underscore before f16 (compiler-confirmed)
#define MFMA16(a,b,c) __builtin_amdgcn_mfma_f32_16x16x16f16(a,b,c,0,0,0)

// ---- workspace layout (bytes) ----
#define WS_COL_LN   0          // f32 [256][256]  LN(emb_column)
#define WS_LNP      262144     // f32 [128][256]  LN(emb_prompt)
#define WS_BASE     393216     // f32 [128][256]  base (prompt-side xp part)
#define WS_BLOG     524288     // f32 [128][256]  base_logits
#define WS_CW16     655360     // f16 CW in MFMA A-fragment order (see k0b)
#define WS_WB16     786432     // half2 [256][256] {w,b} interleaved feature emb

// ---- main LDS (bytes) ----
// x_s 1K @0 | sm_m 1K @1024 | sm_l 1K @2048 |
// region @3072: phase1 CW 128 KB; phase2 reuse: P 64 KB @3072,
//               xe dbuf 2x32 KB @68608/@101376 (overlaps dead CW upper half)
#define LDS_CWP   3072
#define LDS_XE0   68608
#define LDS_XE1   101376
#define SMEM_MAIN 134144       // 1 block/CU; 16 waves = 4/SIMD

// ============================ stage 0 kernels ============================

__global__ __launch_bounds__(256) void k0a(
    const float* __restrict__ emb_column, const float* __restrict__ emb_prompt,
    const float* __restrict__ ln_col_g, const float* __restrict__ ln_col_b,
    const float* __restrict__ ln_prompt_g, const float* __restrict__ ln_prompt_b,
    const float* __restrict__ few, const float* __restrict__ feb,
    char* __restrict__ ws)
{
    __shared__ float red[10];
    int blk = blockIdx.x, tid = threadIdx.x;
    if (blk < 384) {
        const float *src, *g, *bb; float* dst;
        if (blk < 256) { int r = blk;     src = emb_column + r*DD; g = ln_col_g;    bb = ln_col_b;    dst = (float*)(ws + WS_COL_LN) + r*DD; }
        else           { int r = blk-256; src = emb_prompt + r*DD; g = ln_prompt_g; bb = ln_prompt_b; dst = (float*)(ws + WS_LNP) + r*DD; }
        float v = src[tid];
        float s = v, q = v*v;
        #pragma unroll
        for (int off = 32; off; off >>= 1) { s += __shfl_xor(s, off); q += __shfl_xor(q, off); }
        int wid = tid >> 6, lane = tid & 63;
        if (lane == 0) { red[wid] = s; red[4+wid] = q; }
        __syncthreads();
        if (tid == 0) {
            float S = red[0]+red[1]+red[2]+red[3];
            float Q = red[4]+red[5]+red[6]+red[7];
            float mu = S * (1.0f/DD);
            float var = Q * (1.0f/DD) - mu*mu;
            red[8] = mu; red[9] = rsqrtf(var + 1e-5f);
        }
        __syncthreads();
        dst[tid] = (v - red[8]) * red[9] * g[tid] + bb[tid];
    } else {
        int base = (blk - 384) * 512;
        half2* wb = (half2*)(ws + WS_WB16);
        #pragma unroll
        for (int j = 0; j < 2; ++j) {
            int idx = base + j*256 + tid;      // 0..65535
            half2 h; h[0] = (_Float16)few[idx]; h[1] = (_Float16)feb[idx];
            wb[idx] = h;
        }
    }
}

// blocks 0..255: CW[n][k] = sum_d col_ln[n][d] * diw[d][256+k], stored in
//   MFMA A-fragment order: f16 index ((kc*16+nt)*64 + lq*16 + lr)*4 + j
//   with n = 16nt+lr, k = 16kc+4lq+j.
// blocks 256..383: base[p][d] = sum_k LNp[p][k]*diw[d][k] + dib[d] + emb_prompt[p][d]
__global__ __launch_bounds__(256) void k0b(
    const float* __restrict__ diw, const float* __restrict__ dib,
    const float* __restrict__ emb_prompt, char* __restrict__ ws)
{
    __shared__ float rowv[DD];
    int blk = blockIdx.x, tid = threadIdx.x;
    if (blk < 256) {
        int n = blk;
        const float* col_ln = (const float*)(ws + WS_COL_LN);
        rowv[tid] = col_ln[n*DD + tid];
        __syncthreads();
        float acc = 0.f;
        #pragma unroll 4
        for (int d = 0; d < DD; ++d) acc += rowv[d] * diw[d*512 + 256 + tid];
        int nt = n >> 4, lr = n & 15;
        int kc = tid >> 4, lq = (tid >> 2) & 3, j = tid & 3;
        ((_Float16*)(ws + WS_CW16))[((kc*16 + nt)*64 + lq*16 + lr)*4 + j] = (_Float16)acc;
    } else {
        int p = blk - 256;
        const float* lnp = (const float*)(ws + WS_LNP);
        rowv[tid] = lnp[p*DD + tid];
        __syncthreads();
        float acc = 0.f;
        #pragma unroll 4
        for (int k = 0; k < DD; ++k) acc += rowv[k] * diw[tid*512 + k];
        ((float*)(ws + WS_BASE))[p*DD + tid] = acc + dib[tid] + emb_prompt[p*DD + tid];
    }
}

// base_logits[p][n] = sum_d base[p][d] * col_ln[n][d]
__global__ __launch_bounds__(256) void k0c(char* __restrict__ ws)
{
    __shared__ float bs[DD];
    int p = blockIdx.x, n = threadIdx.x;
    const float* base   = (const float*)(ws + WS_BASE);
    const float* col_ln = (const float*)(ws + WS_COL_LN);
    bs[n] = base[p*DD + n];
    __syncthreads();
    float acc = 0.f;
    #pragma unroll 4
    for (int d = 0; d < DD; ++d) acc += bs[d] * col_ln[n*DD + d];
    ((float*)(ws + WS_BLOG))[p*DD + n] = acc;
}

// ============================ main kernel ============================
// 1 block = 1 batch (grid 1024, 1024 thr, 16 waves = 4/SIMD).
// Wave w: p-tile pt=w>>1 (16 rows), half h=w&1 (n-half in P1, d-half in P2).
// Phase 1 (logits): CW loaded ONCE to LDS (128 KB, no chunking) -> one
//   barrier-free 128-MFMA stretch per wave; acc 8xf32x4 (32 AGPR),
//   pfrag 32 VGPR -> ~104 regs < 128 cap.
// Softmax: in-lane + 2 shfl + pair-combine via 1KB LDS.
// P (f16, normalized) -> LDS over dead CW region, XOR-swizzled (G4).
// Phase 2 (PV): xe computed per 64-n chunk into LDS dbuf (never HBM),
//   P read as B-frags from LDS; acc_v 8xf32x4 (32 AGPR) -> ~100 regs.
__global__ __launch_bounds__(1024) void trompt_main(
    const float* __restrict__ x, const float* __restrict__ prev,
    const float* __restrict__ expand_w, const float* __restrict__ expand_b,
    const float* __restrict__ ln_emb_g, const float* __restrict__ ln_emb_b,
    const char* __restrict__ ws, float* __restrict__ out)
{
    extern __shared__ char smem[];
    float* x_s  = (float*)(smem);
    float* sm_m = (float*)(smem + 1024);
    float* sm_l = (float*)(smem + 2048);
    char*  cwP  = smem + LDS_CWP;        // CW (P1) then P (P2)
    char*  xe0  = smem + LDS_XE0;
    char*  xe1  = smem + LDS_XE1;

    const char*  cwbase = ws + WS_CW16;
    const half2* WB     = (const half2*)(ws + WS_WB16);

    int b = blockIdx.x;
    int tid = threadIdx.x;
    int w = tid >> 6, l = tid & 63, lq = l >> 4, lr = l & 15;
    int pt = w >> 1, h = w & 1;
    int p  = 16*pt + lr;
    int pswz = (p & 7) << 4;

    if (tid < 256) x_s[tid] = x[b*NCOLS + tid];

    // cooperative CW load: 1024 thr x 8 x 16B = 131072 B = 128 KB
    // (R14 bug: was x2 -> only 32 KB loaded, fragments kc>=4 garbage -> NaN)
    #pragma unroll
    for (int i = 0; i < 8; ++i) {
        int u = tid + 1024*i;
        *(uint4*)(cwP + u*16) = *(const uint4*)(cwbase + u*16);
    }

    // prev row -> f16 B-fragments (32 VGPRs); pair duplicates (L2 hit)
    half4 pfrag[16];
    {
        const float* prow = prev + ((size_t)b*NP + p)*DD + 4*lq;
        #pragma unroll
        for (int kc = 0; kc < 16; ++kc) {
            f32x4 v = *(const f32x4*)(prow + 16*kc);
            half4 hh;
            #pragma unroll
            for (int j = 0; j < 4; ++j) hh[j] = (_Float16)v[j];
            pfrag[kc] = hh;
        }
    }

    // C-init from base_logits: acc[a] <-> n-tile nt = 8h + a
    f32x4 acc[8];
    {
        const float* blrow = (const float*)(ws + WS_BLOG) + (size_t)p*DD + 4*lq;
        #pragma unroll
        for (int a = 0; a < 8; ++a) acc[a] = *(const f32x4*)(blrow + 16*(8*h + a));
    }

    __syncthreads();                 // CW + x_s ready

    // ---- Phase 1: logits, barrier-free 128-MFMA stretch ----
    {
        const char* cwl = cwP + l*8 + (size_t)(8*h)*512;
        #pragma unroll
        for (int kc = 0; kc < 16; ++kc) {
            const char* fb = cwl + (size_t)kc*8192;
            half4 bp = pfrag[kc];
            #pragma unroll
            for (int a = 0; a < 8; ++a)
                acc[a] = MFMA16(*(const half4*)(fb + a*512), bp, acc[a]);
        }
    }

    // ---- softmax over full n-row (pair halves combined via LDS) ----
    float pmax = -1e30f;
    #pragma unroll
    for (int a = 0; a < 8; ++a)
        #pragma unroll
        for (int r = 0; r < 4; ++r) pmax = fmaxf(pmax, acc[a][r]);
    pmax = fmaxf(pmax, __shfl_xor(pmax, 16));
    pmax = fmaxf(pmax, __shfl_xor(pmax, 32));
    if (lq == 0) sm_m[h*128 + p] = pmax;
    __syncthreads();
    float m = fmaxf(pmax, sm_m[(1 ^ h)*128 + p]);

    float s = 0.f;
    #pragma unroll
    for (int a = 0; a < 8; ++a)
        #pragma unroll
        for (int r = 0; r < 4; ++r) { float e = __expf(acc[a][r] - m); acc[a][r] = e; s += e; }
    s += __shfl_xor(s, 16);
    s += __shfl_xor(s, 32);
    if (lq == 0) sm_l[h*128 + p] = s;
    __syncthreads();                 // also: all waves done reading CW
    float inv = 1.0f / (s + sm_l[(1 ^ h)*128 + p]);

    // ---- write normalized P (f16) over dead CW region, swizzled ----
    #pragma unroll
    for (int a = 0; a < 8; ++a) {
        int nb = (8*h + a)*32 + lq*8;        // byte offset of n*2 within row
        half4 hh;
        #pragma unroll
        for (int r = 0; r < 4; ++r) hh[r] = (_Float16)(acc[a][r] * inv);
        *(half4*)(cwP + p*512 + (nb ^ pswz)) = hh;
    }

    // ---- Phase 2 prologue ----
    float gcc[4], bcc[4];
    #pragma unroll
    for (int cc = 0; cc < 4; ++cc) {
        gcc[cc] = ln_emb_g[l + 64*cc];
        bcc[cc] = ln_emb_b[l + 64*cc];
    }

    // xe chunk compute: 64 n-rows -> f16 fragment buffer; 4 rows/wave.
    // chunk-local n = 16*kc2w + 4*lq2 + j (kc2w = w>>2, lq2 = w&3)
    auto compute_xe = [&](int c, char* xebuf) {
        int kc2w = w >> 2, lq2 = w & 3;
        float vj[4][4];
        #pragma unroll
        for (int j = 0; j < 4; ++j) {
            int n = c*64 + 16*kc2w + 4*lq2 + j;
            float xv = x_s[n];
            const half2* wbrow = WB + n*DD;
            float ss = 0.f, qq = 0.f;
            #pragma unroll
            for (int cc = 0; cc < 4; ++cc) {
                half2 pp = wbrow[l + 64*cc];
                float e = fmaf(xv, (float)pp[0], (float)pp[1]);
                e = e > 0.f ? e : 0.f;
                vj[j][cc] = e; ss += e; qq += e*e;
            }
            #pragma unroll
            for (int off = 32; off; off >>= 1) { ss += __shfl_xor(ss, off); qq += __shfl_xor(qq, off); }
            float mu = ss * (1.0f/DD);
            float rs = rsqrtf(qq*(1.0f/DD) - mu*mu + 1e-5f);
            #pragma unroll
            for (int cc = 0; cc < 4; ++cc)
                vj[j][cc] = (vj[j][cc]-mu)*rs*gcc[cc] + bcc[cc];
        }
        #pragma unroll
        for (int cc = 0; cc < 4; ++cc) {
            int dt = 4*cc + (l >> 4);
            half4 hh;
            #pragma unroll
            for (int j = 0; j < 4; ++j) hh[j] = (_Float16)vj[j][cc];
            *(half4*)(xebuf + (((kc2w*16 + dt)*64) + lq2*16 + lr)*8) = hh;
        }
    };

    compute_xe(0, xe0);

    f32x4 acc_v[8];                  // 16p x 128d: d = 128h + 16dtl + 4lq + r
    #pragma unroll
    for (int dtl = 0; dtl < 8; ++dtl) acc_v[dtl] = (f32x4){0.f,0.f,0.f,0.f};

    __syncthreads();                 // P + xe0 complete

    for (int c = 0; c < 4; ++c) {
        char* xec = (c & 1) ? xe1 : xe0;
        char* xen = (c & 1) ? xe0 : xe1;

        // P B-fragments for this chunk (ds_read, swizzled, ~2-way free)
        half4 bp[4];
        #pragma unroll
        for (int kc2 = 0; kc2 < 4; ++kc2)
            bp[kc2] = *(const half4*)(cwP + p*512 + ((c*128 + kc2*32 + lq*8) ^ pswz));

        if (c < 3) compute_xe(c+1, xen);

        const char* xel = xec + l*8;
        #pragma unroll
        for (int kc2 = 0; kc2 < 4; ++kc2) {
            const char* xb = xel + (size_t)(kc2*16 + 8*h)*512;
            half4 bpc = bp[kc2];
            #pragma unroll
            for (int dtl = 0; dtl < 8; ++dtl)
                acc_v[dtl] = MFMA16(*(const half4*)(xb + dtl*512), bpc, acc_v[dtl]);
        }

        if (c < 3) __syncthreads();  // xen complete; xec free to overwrite
    }

    // epilogue: out = V*sw + sb (P pre-normalized); d-half per wave
    {
        float sw = 1.0f + expand_w[p];
        float sb = expand_b[p];
        float* orow = out + ((size_t)b*NP + p)*DD + 128*h + 4*lq;
        #pragma unroll
        for (int dtl = 0; dtl < 8; ++dtl) {
            f32x4 v = acc_v[dtl];
            #pragma unroll
            for (int r = 0; r < 4; ++r) v[r] = v[r]*sw + sb;
            *(f32x4*)(orow + 16*dtl) = v;
        }
    }
}

// ============================ launcher ============================
extern "C" void kernel_launch(void* const* d_in, const int* in_sizes, int n_in,
                              void* d_out, int out_size, void* d_ws, size_t ws_size,
                              hipStream_t stream) {
    (void)in_sizes; (void)n_in; (void)out_size; (void)ws_size;
    const float* x           = (const float*)d_in[0];
    const float* prev        = (const float*)d_in[1];
    const float* few         = (const float*)d_in[2];
    const float* feb         = (const float*)d_in[3];
    const float* ln_emb_g    = (const float*)d_in[4];
    const float* ln_emb_b    = (const float*)d_in[5];
    const float* ln_col_g    = (const float*)d_in[6];
    const float* ln_col_b    = (const float*)d_in[7];
    const float* ln_prompt_g = (const float*)d_in[8];
    const float* ln_prompt_b = (const float*)d_in[9];
    const float* diw         = (const float*)d_in[10];
    const float* dib         = (const float*)d_in[11];
    const float* emb_column  = (const float*)d_in[12];
    const float* emb_prompt  = (const float*)d_in[13];
    const float* expand_w    = (const float*)d_in[14];
    const float* expand_b    = (const float*)d_in[15];
    char* ws = (char*)d_ws;
    float* out = (float*)d_out;

    k0a<<<512, 256, 0, stream>>>(emb_column, emb_prompt, ln_col_g, ln_col_b,
                                 ln_prompt_g, ln_prompt_b, few, feb, ws);
    k0b<<<384, 256, 0, stream>>>(diw, dib, emb_prompt, ws);
    k0c<<<128, 256, 0, stream>>>(ws);

    (void)hipFuncSetAttribute(reinterpret_cast<const void*>(trompt_main),
                              hipFuncAttributeMaxDynamicSharedMemorySize, SMEM_MAIN);
    trompt_main<<<1024, 1024, SMEM_MAIN, stream>>>(x, prev, expand_w, expand_b,
                                                   ln_emb_g, ln_emb_b, ws, out);
}